// Round 2
// baseline (493.806 us; speedup 1.0000x reference)
//
#include <hip/hip_runtime.h>
#include <hip/hip_bf16.h>

// Problem constants
#define S_LEN  1024
#define DMODEL 1024
#define NHEADS 16
#define DK     64
#define SCALE  0.125f
// rel table: 257 rows; padded to 272 (relk, 17 n-tiles) and 288 (rvT K-pad)

typedef __bf16 bf16x8_t __attribute__((ext_vector_type(8)));
typedef __bf16 bf16x4_t __attribute__((ext_vector_type(4)));
typedef float  f32x4_t  __attribute__((ext_vector_type(4)));

#define MFMA16(A, B, C) __builtin_amdgcn_mfma_f32_16x16x32_bf16((A), (B), (C), 0, 0, 0)

__device__ __forceinline__ void async16(const void* g, void* l) {
    __builtin_amdgcn_global_load_lds(
        (const __attribute__((address_space(1))) unsigned int*)g,
        (__attribute__((address_space(3))) unsigned int*)l, 16, 0, 0);
}

// ---------------------------------------------------------------------------
// Kernel 1: cast inputs to bf16 + build padded rel tables.
// Regions (vec4 indices): X (q,k,v) 3*1048576 (z=0 also writes Xqlo residual) |
// W (wq,wk,wv,wo) 4*262144 (z=0 also writes Wqlo residual) |
// relk hi+lo padded 272x64 -> 4352 | rvT (transposed rel_v, 64x288 pad) 4608
__global__ __launch_bounds__(256) void cast_all_kernel(
    const float* __restrict__ q, const float* __restrict__ k, const float* __restrict__ v,
    const float* __restrict__ wq, const float* __restrict__ wk,
    const float* __restrict__ wv, const float* __restrict__ wo,
    const float* __restrict__ relk, const float* __restrict__ relv,
    __bf16* __restrict__ Xbf, __bf16* __restrict__ Wall,
    __bf16* __restrict__ relkp, __bf16* __restrict__ rvT,
    __bf16* __restrict__ Xqlo, __bf16* __restrict__ Wqlo)
{
    const long i = (long)blockIdx.x * 256 + threadIdx.x;   // vec4 index
    if (i < 3145728) {                       // X region
        const int z   = (int)(i >> 20);
        const long rem = i & 1048575;
        const float4 s = ((const float4*)(z == 0 ? q : (z == 1 ? k : v)))[rem];
        const float xs[4] = {s.x, s.y, s.z, s.w};
        bf16x4_t h;
        #pragma unroll
        for (int t = 0; t < 4; ++t) h[t] = (__bf16)xs[t];
        *(bf16x4_t*)(Xbf + ((size_t)z << 22) + rem * 4) = h;
        if (z == 0) {
            bf16x4_t l;
            #pragma unroll
            for (int t = 0; t < 4; ++t) l[t] = (__bf16)(xs[t] - (float)h[t]);
            *(bf16x4_t*)(Xqlo + rem * 4) = l;
        }
    } else if (i < 3145728 + 1048576) {      // W region
        const long wi = i - 3145728;
        const int z   = (int)(wi >> 18);
        const long rem = wi & 262143;
        const float* src = (z == 0) ? wq : (z == 1) ? wk : (z == 2) ? wv : wo;
        const float4 s = ((const float4*)src)[rem];
        const float xs[4] = {s.x, s.y, s.z, s.w};
        bf16x4_t h;
        #pragma unroll
        for (int t = 0; t < 4; ++t) h[t] = (__bf16)xs[t];
        *(bf16x4_t*)(Wall + ((size_t)z << 20) + rem * 4) = h;
        if (z == 0) {
            bf16x4_t l;
            #pragma unroll
            for (int t = 0; t < 4; ++t) l[t] = (__bf16)(xs[t] - (float)h[t]);
            *(bf16x4_t*)(Wqlo + rem * 4) = l;
        }
    } else if (i < 3145728 + 1048576 + 4352) {   // relk hi+lo (272 rows x 64)
        const long ri = i - (3145728 + 1048576);
        const int j  = (int)(ri >> 4);
        const int d4 = (int)(ri & 15) * 4;
        bf16x4_t h, l;
        if (j < 257) {
            const float4 s = *(const float4*)(relk + j * 64 + d4);
            const float xs[4] = {s.x, s.y, s.z, s.w};
            #pragma unroll
            for (int t = 0; t < 4; ++t) {
                h[t] = (__bf16)xs[t];
                l[t] = (__bf16)(xs[t] - (float)h[t]);
            }
        } else {
            #pragma unroll
            for (int t = 0; t < 4; ++t) { h[t] = (__bf16)0.f; l[t] = (__bf16)0.f; }
        }
        *(bf16x4_t*)(relkp + j * 64 + d4) = h;
        *(bf16x4_t*)(relkp + 17408 + j * 64 + d4) = l;
    } else if (i < 3145728 + 1048576 + 4352 + 4608) { // rvT: [64][288], rvT[d][j]=rel_v[j][d]
        const long ri = i - (3145728 + 1048576 + 4352);
        const int d  = (int)(ri / 72);
        const int j4 = (int)(ri % 72) * 4;
        bf16x4_t o;
        #pragma unroll
        for (int t = 0; t < 4; ++t) {
            const int j = j4 + t;
            o[t] = (j < 257) ? (__bf16)relv[j * 64 + d] : (__bf16)0.f;
        }
        *(bf16x4_t*)(rvT + d * 288 + j4) = o;
    }
}

// ---------------------------------------------------------------------------
// Shared 128x128 tile GEMM core: acc += A(128xK) @ W(128xK)^T, K=1024, BK=32.
// m97 structure: global_load_lds width-16 staging, 16x16x32 bf16 MFMA, 4x4 acc/wave.
// NOTE: caller zeroes acc (so split-K hi/lo passes can accumulate).
__device__ __forceinline__ void gemm128_core(
    const __bf16* __restrict__ A, const __bf16* __restrict__ W,
    __bf16* As, __bf16* Ws, f32x4_t acc[4][4])
{
    const int tid  = threadIdx.x;
    const int lane = tid & 63;
    const int quad = lane >> 4;
    const int l15  = lane & 15;
    const int wid  = tid >> 6;
    const int wm = wid >> 1, wn = wid & 1;

    for (int kt = 0; kt < 32; ++kt) {
        #pragma unroll
        for (int r = 0; r < 2; ++r) {
            const int c = r * 256 + tid;        // 512 chunks of 16B per tile
            const int row = c >> 2, kb = c & 3;
            async16(A + row * 1024 + kt * 32 + kb * 8, As + c * 8);
            async16(W + row * 1024 + kt * 32 + kb * 8, Ws + c * 8);
        }
        __syncthreads();                        // drains vmcnt for global_load_lds
        bf16x8_t af[4], wf[4];
        #pragma unroll
        for (int i = 0; i < 4; ++i) {
            af[i] = *(const bf16x8_t*)(As + (wm * 64 + i * 16 + l15) * 32 + quad * 8);
            wf[i] = *(const bf16x8_t*)(Ws + (wn * 64 + i * 16 + l15) * 32 + quad * 8);
        }
        #pragma unroll
        for (int i = 0; i < 4; ++i)
            #pragma unroll
            for (int j = 0; j < 4; ++j)
                acc[i][j] = MFMA16(af[i], wf[j], acc[i][j]);
        __syncthreads();
    }
}

// ---------------------------------------------------------------------------
// Kernel 2: QKV projections. z=0:Q (split-K hi/lo for extra precision),
// z=1:K written [bh][s][d]; z=2:V written transposed [bh][d][s].
__global__ __launch_bounds__(256) void gemm_qkv_kernel(
    const __bf16* __restrict__ Xbf, const __bf16* __restrict__ Wall,
    const __bf16* __restrict__ Xqlo, const __bf16* __restrict__ Wqlo,
    const float* __restrict__ bq, const float* __restrict__ bk, const float* __restrict__ bv,
    __bf16* __restrict__ QKVh)
{
    __shared__ __bf16 As[4096], Ws[4096];
    const int z = blockIdx.z;
    const __bf16* A = Xbf + (size_t)z * 4194304 + (size_t)blockIdx.y * 131072;
    const __bf16* W = Wall + (size_t)z * 1048576 + (size_t)blockIdx.x * 131072;
    f32x4_t acc[4][4];
    #pragma unroll
    for (int i = 0; i < 4; ++i)
        #pragma unroll
        for (int j = 0; j < 4; ++j)
            acc[i][j] = (f32x4_t){0.f, 0.f, 0.f, 0.f};

    gemm128_core(A, W, As, Ws, acc);
    if (z == 0) {
        // Q = Xhi*Whi + Xhi*Wlo + Xlo*Whi  (drop lo*lo)
        gemm128_core(A, Wqlo + (size_t)blockIdx.x * 131072, As, Ws, acc);
        gemm128_core(Xqlo + (size_t)blockIdx.y * 131072, W, As, Ws, acc);
    }

    const int tid = threadIdx.x, lane = tid & 63, quad = lane >> 4, l15 = lane & 15;
    const int wid = tid >> 6, wm = wid >> 1, wn = wid & 1;
    const int m0 = blockIdx.y * 128 + wm * 64;
    const int n0 = blockIdx.x * 128 + wn * 64;
    const float* bias = (z == 0) ? bq : ((z == 1) ? bk : bv);
    __bf16* dst = QKVh + (size_t)z * 4194304;

    if (z < 2) {
        #pragma unroll
        for (int j = 0; j < 4; ++j) {
            const int n = n0 + j * 16 + l15;
            const float bn = bias[n];
            #pragma unroll
            for (int i = 0; i < 4; ++i) {
                #pragma unroll
                for (int v = 0; v < 4; ++v) {
                    const int m = m0 + i * 16 + quad * 4 + v;
                    dst[((((m >> 10) * 16 + (n >> 6)) << 16)) + ((m & 1023) << 6) + (n & 63)]
                        = (__bf16)(acc[i][j][v] + bn);
                }
            }
        }
    } else {
        #pragma unroll
        for (int j = 0; j < 4; ++j) {
            const int n = n0 + j * 16 + l15;
            const float bn = bias[n];
            #pragma unroll
            for (int i = 0; i < 4; ++i) {
                const int m = m0 + i * 16 + quad * 4;   // 4 consecutive s -> pack 8B
                bf16x4_t pk;
                #pragma unroll
                for (int v = 0; v < 4; ++v) pk[v] = (__bf16)(acc[i][j][v] + bn);
                *(bf16x4_t*)(dst + (((m >> 10) * 16 + (n >> 6)) << 16)
                                 + ((n & 63) << 10) + (m & 1023)) = pk;
            }
        }
    }
}

// ---------------------------------------------------------------------------
// Kernel 4: output projection, fp32 epilogue straight to d_out.
__global__ __launch_bounds__(256) void gemm_out_kernel(
    const __bf16* __restrict__ ctx, const __bf16* __restrict__ Wo,
    const float* __restrict__ bo, float* __restrict__ out)
{
    __shared__ __bf16 As[4096], Ws[4096];
    const __bf16* A = ctx + (size_t)blockIdx.y * 131072;
    const __bf16* W = Wo + (size_t)blockIdx.x * 131072;
    f32x4_t acc[4][4];
    #pragma unroll
    for (int i = 0; i < 4; ++i)
        #pragma unroll
        for (int j = 0; j < 4; ++j)
            acc[i][j] = (f32x4_t){0.f, 0.f, 0.f, 0.f};
    gemm128_core(A, W, As, Ws, acc);

    const int tid = threadIdx.x, lane = tid & 63, quad = lane >> 4, l15 = lane & 15;
    const int wid = tid >> 6, wm = wid >> 1, wn = wid & 1;
    const int m0 = blockIdx.y * 128 + wm * 64;
    const int n0 = blockIdx.x * 128 + wn * 64;
    #pragma unroll
    for (int j = 0; j < 4; ++j) {
        const int n = n0 + j * 16 + l15;
        const float bn = bo[n];
        #pragma unroll
        for (int i = 0; i < 4; ++i)
            #pragma unroll
            for (int v = 0; v < 4; ++v) {
                const int m = m0 + i * 16 + quad * 4 + v;
                out[(size_t)m * 1024 + n] = acc[i][j][v] + bn;
            }
    }
}

// ---------------------------------------------------------------------------
// Kernel 3: fused attention. Block = 128 threads (2 waves); each wave owns a
// 16-row Q tile. Single-pass softmax (no max-subtract: fp32 exp handles range).
// qrel (Q @ rel_k^T, rel_k split hi/lo) computed in-kernel into *fp32* LDS;
// rel_v handled via 257-bin prob histogram w (interior bin = single prob;
// edge bins summed), then w @ rel_v^T MFMA'd into the same O accumulators.
__global__ __launch_bounds__(128) void attn_kernel(
    const __bf16* __restrict__ Qh, const __bf16* __restrict__ Kh,
    const __bf16* __restrict__ VhT, const __bf16* __restrict__ relkp,
    const __bf16* __restrict__ rvT, const int* __restrict__ mask,
    __bf16* __restrict__ ctx)
{
    __shared__ float  qrel_s[2][16][272];   // fp32: bias precision matters
    __shared__ __bf16 w_s[2][16][288];
    __shared__ __bf16 p_s[2][16][32];

    const int tid = threadIdx.x, lane = tid & 63, wid = tid >> 6;
    const int quad = lane >> 4, l15 = lane & 15;
    const int bh = blockIdx.y;
    const int b  = bh >> 4;
    const int l0 = blockIdx.x * 32 + wid * 16;  // global q-row base for this wave

    const __bf16* Qbase = Qh  + (size_t)bh * 65536;
    const __bf16* Kbase = Kh  + (size_t)bh * 65536;
    const __bf16* Vbase = VhT + (size_t)bh * 65536;
    const __bf16* relk_hi = relkp;
    const __bf16* relk_lo = relkp + 17408;

    // Q A-frags (reused for both qrel and QK^T)
    const bf16x8_t aq0 = *(const bf16x8_t*)(Qbase + (l0 + l15) * 64 + quad * 8);
    const bf16x8_t aq1 = *(const bf16x8_t*)(Qbase + (l0 + l15) * 64 + 32 + quad * 8);

    // zero the w-bin array (16x288 bf16 per wave)
    {
        unsigned int* wz = (unsigned int*)&w_s[wid][0][0];
        for (int t = lane; t < 2304; t += 64) wz[t] = 0u;
    }

    // qrel[lrow][j] = Q[l]·rel_k[j], j in [0,272); rel_k = hi + lo
    for (int nt = 0; nt < 17; ++nt) {
        const int j = nt * 16 + l15;
        const bf16x8_t h0 = *(const bf16x8_t*)(relk_hi + j * 64 + quad * 8);
        const bf16x8_t h1 = *(const bf16x8_t*)(relk_hi + j * 64 + 32 + quad * 8);
        const bf16x8_t lo0 = *(const bf16x8_t*)(relk_lo + j * 64 + quad * 8);
        const bf16x8_t lo1 = *(const bf16x8_t*)(relk_lo + j * 64 + 32 + quad * 8);
        f32x4_t c = (f32x4_t){0.f, 0.f, 0.f, 0.f};
        c = MFMA16(aq0, lo0, c);
        c = MFMA16(aq1, lo1, c);
        c = MFMA16(aq0, h0, c);
        c = MFMA16(aq1, h1, c);
        #pragma unroll
        for (int v = 0; v < 4; ++v) qrel_s[wid][quad * 4 + v][j] = c[v];
    }
    __syncthreads();

    f32x4_t o[4];
    #pragma unroll
    for (int dt = 0; dt < 4; ++dt) o[dt] = (f32x4_t){0.f, 0.f, 0.f, 0.f};
    float rowsum[4] = {0.f, 0.f, 0.f, 0.f};
    float e0[4] = {0.f, 0.f, 0.f, 0.f};
    float e1[4] = {0.f, 0.f, 0.f, 0.f};

    for (int rc = 0; rc < 32; ++rc) {
        const int r0 = rc * 32;
        #pragma unroll
        for (int nt = 0; nt < 2; ++nt) {
            const int r = r0 + nt * 16 + l15;
            const bf16x8_t kb0 = *(const bf16x8_t*)(Kbase + r * 64 + quad * 8);
            const bf16x8_t kb1 = *(const bf16x8_t*)(Kbase + r * 64 + 32 + quad * 8);
            f32x4_t s = (f32x4_t){0.f, 0.f, 0.f, 0.f};
            s = MFMA16(aq0, kb0, s);
            s = MFMA16(aq1, kb1, s);
            const float madd = (mask[b * 1024 + r] == 0) ? -1.0e9f : 0.f;
            #pragma unroll
            for (int v = 0; v < 4; ++v) {
                const int lrow = quad * 4 + v;
                const int l = l0 + lrow;
                const int dd = r - l;
                const int j = (dd < -128) ? 0 : ((dd > 128) ? 256 : dd + 128);
                const float bias = qrel_s[wid][lrow][j];
                const float p = __expf(s[v] * SCALE + bias + madd);
                const __bf16 pb = (__bf16)p;
                const float pf = (float)pb;     // consistent with what MFMAs consume
                rowsum[v] += pf;
                p_s[wid][lrow][nt * 16 + l15] = pb;
                if (j == 0)        e0[v] += pf;
                else if (j == 256) e1[v] += pf;
                else               w_s[wid][lrow][j] = pb;
            }
        }
        __syncthreads();
        const bf16x8_t pa = *(const bf16x8_t*)(&p_s[wid][l15][quad * 8]);
        #pragma unroll
        for (int dt = 0; dt < 4; ++dt) {
            const bf16x8_t vb =
                *(const bf16x8_t*)(Vbase + (dt * 16 + l15) * 1024 + r0 + quad * 8);
            o[dt] = MFMA16(pa, vb, o[dt]);
        }
        __syncthreads();
    }

    // reduce row sums / edge bins across the 16 lanes of each quad
    #pragma unroll
    for (int v = 0; v < 4; ++v) {
        #pragma unroll
        for (int mm = 1; mm < 16; mm <<= 1) {
            rowsum[v] += __shfl_xor(rowsum[v], mm, 64);
            e0[v]     += __shfl_xor(e0[v], mm, 64);
            e1[v]     += __shfl_xor(e1[v], mm, 64);
        }
    }
    if (l15 == 0) {
        #pragma unroll
        for (int v = 0; v < 4; ++v) {
            w_s[wid][quad * 4 + v][0]   = (__bf16)e0[v];
            w_s[wid][quad * 4 + v][256] = (__bf16)e1[v];
        }
    }
    __syncthreads();

    // O += w @ rel_v (K padded to 288 with zeros)
    for (int kc = 0; kc < 9; ++kc) {
        const bf16x8_t wa = *(const bf16x8_t*)(&w_s[wid][l15][kc * 32 + quad * 8]);
        #pragma unroll
        for (int dt = 0; dt < 4; ++dt) {
            const bf16x8_t rb =
                *(const bf16x8_t*)(rvT + (dt * 16 + l15) * 288 + kc * 32 + quad * 8);
            o[dt] = MFMA16(wa, rb, o[dt]);
        }
    }

    // epilogue: fold in 1/rowsum, store ctx [b][s][h*64+d] bf16
    float rinv[4];
    #pragma unroll
    for (int v = 0; v < 4; ++v) rinv[v] = 1.f / rowsum[v];
    const int h = bh & 15;
    #pragma unroll
    for (int dt = 0; dt < 4; ++dt)
        #pragma unroll
        for (int v = 0; v < 4; ++v) {
            const int l = l0 + quad * 4 + v;
            ctx[((size_t)b * 1024 + l) * 1024 + h * 64 + dt * 16 + l15]
                = (__bf16)(o[dt][v] * rinv[v]);
        }
}

// ---------------------------------------------------------------------------
extern "C" void kernel_launch(void* const* d_in, const int* in_sizes, int n_in,
                              void* d_out, int out_size, void* d_ws, size_t ws_size,
                              hipStream_t stream)
{
    const float* q    = (const float*)d_in[0];
    const float* k    = (const float*)d_in[1];
    const float* v    = (const float*)d_in[2];
    const int*   mask = (const int*)  d_in[3];
    const float* wq   = (const float*)d_in[4];
    const float* bq   = (const float*)d_in[5];
    const float* wk   = (const float*)d_in[6];
    const float* bk   = (const float*)d_in[7];
    const float* wv   = (const float*)d_in[8];
    const float* bv   = (const float*)d_in[9];
    const float* wo   = (const float*)d_in[10];
    const float* bo   = (const float*)d_in[11];
    const float* relk = (const float*)d_in[12];
    const float* relv = (const float*)d_in[13];

    // workspace layout (bf16 elements); total 38,850,560 elems = 77.7 MB
    __bf16* Xbf   = (__bf16*)d_ws;            // 3 * 4194304
    __bf16* Wall  = Xbf   + 12582912;         // 4 * 1048576 (wq,wk,wv,wo)
    __bf16* QKVh  = Wall  + 4194304;          // 3 * 4194304 (Q,K row; V transposed)
    __bf16* ctx   = QKVh  + 12582912;         // 4194304
    __bf16* relkp = ctx   + 4194304;          // 2 * 272*64 = 34816 (hi | lo)
    __bf16* rvT   = relkp + 34816;            // 64*288 = 18432
    __bf16* Xqlo  = rvT   + 18432;            // 4194304 (query input residual)
    __bf16* Wqlo  = Xqlo  + 4194304;          // 1048576 (wq residual)

    cast_all_kernel<<<16419, 256, 0, stream>>>(q, k, v, wq, wk, wv, wo, relk, relv,
                                               Xbf, Wall, relkp, rvT, Xqlo, Wqlo);
    gemm_qkv_kernel<<<dim3(8, 32, 3), 256, 0, stream>>>(Xbf, Wall, Xqlo, Wqlo,
                                                        bq, bk, bv, QKVh);
    attn_kernel<<<dim3(32, 64), 128, 0, stream>>>(QKVh, QKVh + 4194304,
                                                  QKVh + 2 * 4194304, relkp, rvT,
                                                  mask, ctx);
    gemm_out_kernel<<<dim3(8, 32, 1), 256, 0, stream>>>(ctx, Wall + 3 * 1048576,
                                                        bo, (float*)d_out);
}

// Round 3
// 433.176 us; speedup vs baseline: 1.1400x; 1.1400x over previous
//
#include <hip/hip_runtime.h>
#include <hip/hip_bf16.h>

// Problem constants
#define S_LEN  1024
#define DMODEL 1024
#define NHEADS 16
#define DK     64
#define SCALE  0.125f
// rel table: 257 rows; padded to 272 (relk, 17 n-tiles) and 288 (rvT K-pad)

typedef __bf16 bf16x8_t __attribute__((ext_vector_type(8)));
typedef __bf16 bf16x4_t __attribute__((ext_vector_type(4)));
typedef float  f32x4_t  __attribute__((ext_vector_type(4)));

#define MFMA16(A, B, C) __builtin_amdgcn_mfma_f32_16x16x32_bf16((A), (B), (C), 0, 0, 0)

__device__ __forceinline__ void async16(const void* g, void* l) {
    __builtin_amdgcn_global_load_lds(
        (const __attribute__((address_space(1))) unsigned int*)g,
        (__attribute__((address_space(3))) unsigned int*)l, 16, 0, 0);
}

// ---------------------------------------------------------------------------
// Kernel 1: cast inputs to bf16 + build padded rel tables.
__global__ __launch_bounds__(256) void cast_all_kernel(
    const float* __restrict__ q, const float* __restrict__ k, const float* __restrict__ v,
    const float* __restrict__ wq, const float* __restrict__ wk,
    const float* __restrict__ wv, const float* __restrict__ wo,
    const float* __restrict__ relk, const float* __restrict__ relv,
    __bf16* __restrict__ Xbf, __bf16* __restrict__ Wall,
    __bf16* __restrict__ relkp, __bf16* __restrict__ rvT,
    __bf16* __restrict__ Xqlo, __bf16* __restrict__ Wqlo)
{
    const long i = (long)blockIdx.x * 256 + threadIdx.x;   // vec4 index
    if (i < 3145728) {                       // X region
        const int z   = (int)(i >> 20);
        const long rem = i & 1048575;
        const float4 s = ((const float4*)(z == 0 ? q : (z == 1 ? k : v)))[rem];
        const float xs[4] = {s.x, s.y, s.z, s.w};
        bf16x4_t h;
        #pragma unroll
        for (int t = 0; t < 4; ++t) h[t] = (__bf16)xs[t];
        *(bf16x4_t*)(Xbf + ((size_t)z << 22) + rem * 4) = h;
        if (z == 0) {
            bf16x4_t l;
            #pragma unroll
            for (int t = 0; t < 4; ++t) l[t] = (__bf16)(xs[t] - (float)h[t]);
            *(bf16x4_t*)(Xqlo + rem * 4) = l;
        }
    } else if (i < 3145728 + 1048576) {      // W region
        const long wi = i - 3145728;
        const int z   = (int)(wi >> 18);
        const long rem = wi & 262143;
        const float* src = (z == 0) ? wq : (z == 1) ? wk : (z == 2) ? wv : wo;
        const float4 s = ((const float4*)src)[rem];
        const float xs[4] = {s.x, s.y, s.z, s.w};
        bf16x4_t h;
        #pragma unroll
        for (int t = 0; t < 4; ++t) h[t] = (__bf16)xs[t];
        *(bf16x4_t*)(Wall + ((size_t)z << 20) + rem * 4) = h;
        if (z == 0) {
            bf16x4_t l;
            #pragma unroll
            for (int t = 0; t < 4; ++t) l[t] = (__bf16)(xs[t] - (float)h[t]);
            *(bf16x4_t*)(Wqlo + rem * 4) = l;
        }
    } else if (i < 3145728 + 1048576 + 4352) {   // relk hi+lo (272 rows x 64)
        const long ri = i - (3145728 + 1048576);
        const int j  = (int)(ri >> 4);
        const int d4 = (int)(ri & 15) * 4;
        bf16x4_t h, l;
        if (j < 257) {
            const float4 s = *(const float4*)(relk + j * 64 + d4);
            const float xs[4] = {s.x, s.y, s.z, s.w};
            #pragma unroll
            for (int t = 0; t < 4; ++t) {
                h[t] = (__bf16)xs[t];
                l[t] = (__bf16)(xs[t] - (float)h[t]);
            }
        } else {
            #pragma unroll
            for (int t = 0; t < 4; ++t) { h[t] = (__bf16)0.f; l[t] = (__bf16)0.f; }
        }
        *(bf16x4_t*)(relkp + j * 64 + d4) = h;
        *(bf16x4_t*)(relkp + 17408 + j * 64 + d4) = l;
    } else if (i < 3145728 + 1048576 + 4352 + 4608) { // rvT: [64][288], rvT[d][j]=rel_v[j][d]
        const long ri = i - (3145728 + 1048576 + 4352);
        const int d  = (int)(ri / 72);
        const int j4 = (int)(ri % 72) * 4;
        bf16x4_t o;
        #pragma unroll
        for (int t = 0; t < 4; ++t) {
            const int j = j4 + t;
            o[t] = (j < 257) ? (__bf16)relv[j * 64 + d] : (__bf16)0.f;
        }
        *(bf16x4_t*)(rvT + d * 288 + j4) = o;
    }
}

// ---------------------------------------------------------------------------
// Shared 128x128 tile GEMM core: acc += A(128xK) @ W(128xK)^T, K=1024, BK=32.
__device__ __forceinline__ void gemm128_core(
    const __bf16* __restrict__ A, const __bf16* __restrict__ W,
    __bf16* As, __bf16* Ws, f32x4_t acc[4][4])
{
    const int tid  = threadIdx.x;
    const int lane = tid & 63;
    const int quad = lane >> 4;
    const int l15  = lane & 15;
    const int wid  = tid >> 6;
    const int wm = wid >> 1, wn = wid & 1;

    for (int kt = 0; kt < 32; ++kt) {
        #pragma unroll
        for (int r = 0; r < 2; ++r) {
            const int c = r * 256 + tid;        // 512 chunks of 16B per tile
            const int row = c >> 2, kb = c & 3;
            async16(A + row * 1024 + kt * 32 + kb * 8, As + c * 8);
            async16(W + row * 1024 + kt * 32 + kb * 8, Ws + c * 8);
        }
        __syncthreads();                        // drains vmcnt for global_load_lds
        bf16x8_t af[4], wf[4];
        #pragma unroll
        for (int i = 0; i < 4; ++i) {
            af[i] = *(const bf16x8_t*)(As + (wm * 64 + i * 16 + l15) * 32 + quad * 8);
            wf[i] = *(const bf16x8_t*)(Ws + (wn * 64 + i * 16 + l15) * 32 + quad * 8);
        }
        #pragma unroll
        for (int i = 0; i < 4; ++i)
            #pragma unroll
            for (int j = 0; j < 4; ++j)
                acc[i][j] = MFMA16(af[i], wf[j], acc[i][j]);
        __syncthreads();
    }
}

// ---------------------------------------------------------------------------
// Kernel 2: QKV projections. z=0:Q (split-K hi/lo), z=1:K [bh][s][d];
// z=2:V transposed [bh][d][s].
__global__ __launch_bounds__(256) void gemm_qkv_kernel(
    const __bf16* __restrict__ Xbf, const __bf16* __restrict__ Wall,
    const __bf16* __restrict__ Xqlo, const __bf16* __restrict__ Wqlo,
    const float* __restrict__ bq, const float* __restrict__ bk, const float* __restrict__ bv,
    __bf16* __restrict__ QKVh)
{
    __shared__ __bf16 As[4096], Ws[4096];
    const int z = blockIdx.z;
    const __bf16* A = Xbf + (size_t)z * 4194304 + (size_t)blockIdx.y * 131072;
    const __bf16* W = Wall + (size_t)z * 1048576 + (size_t)blockIdx.x * 131072;
    f32x4_t acc[4][4];
    #pragma unroll
    for (int i = 0; i < 4; ++i)
        #pragma unroll
        for (int j = 0; j < 4; ++j)
            acc[i][j] = (f32x4_t){0.f, 0.f, 0.f, 0.f};

    gemm128_core(A, W, As, Ws, acc);
    if (z == 0) {
        gemm128_core(A, Wqlo + (size_t)blockIdx.x * 131072, As, Ws, acc);
        gemm128_core(Xqlo + (size_t)blockIdx.y * 131072, W, As, Ws, acc);
    }

    const int tid = threadIdx.x, lane = tid & 63, quad = lane >> 4, l15 = lane & 15;
    const int wid = tid >> 6, wm = wid >> 1, wn = wid & 1;
    const int m0 = blockIdx.y * 128 + wm * 64;
    const int n0 = blockIdx.x * 128 + wn * 64;
    const float* bias = (z == 0) ? bq : ((z == 1) ? bk : bv);
    __bf16* dst = QKVh + (size_t)z * 4194304;

    if (z < 2) {
        #pragma unroll
        for (int j = 0; j < 4; ++j) {
            const int n = n0 + j * 16 + l15;
            const float bn = bias[n];
            #pragma unroll
            for (int i = 0; i < 4; ++i) {
                #pragma unroll
                for (int v = 0; v < 4; ++v) {
                    const int m = m0 + i * 16 + quad * 4 + v;
                    dst[((((m >> 10) * 16 + (n >> 6)) << 16)) + ((m & 1023) << 6) + (n & 63)]
                        = (__bf16)(acc[i][j][v] + bn);
                }
            }
        }
    } else {
        #pragma unroll
        for (int j = 0; j < 4; ++j) {
            const int n = n0 + j * 16 + l15;
            const float bn = bias[n];
            #pragma unroll
            for (int i = 0; i < 4; ++i) {
                const int m = m0 + i * 16 + quad * 4;
                bf16x4_t pk;
                #pragma unroll
                for (int v = 0; v < 4; ++v) pk[v] = (__bf16)(acc[i][j][v] + bn);
                *(bf16x4_t*)(dst + (((m >> 10) * 16 + (n >> 6)) << 16)
                                 + ((n & 63) << 10) + (m & 1023)) = pk;
            }
        }
    }
}

// ---------------------------------------------------------------------------
// Kernel 4: output projection, fp32 epilogue straight to d_out.
__global__ __launch_bounds__(256) void gemm_out_kernel(
    const __bf16* __restrict__ ctx, const __bf16* __restrict__ Wo,
    const float* __restrict__ bo, float* __restrict__ out)
{
    __shared__ __bf16 As[4096], Ws[4096];
    const __bf16* A = ctx + (size_t)blockIdx.y * 131072;
    const __bf16* W = Wo + (size_t)blockIdx.x * 131072;
    f32x4_t acc[4][4];
    #pragma unroll
    for (int i = 0; i < 4; ++i)
        #pragma unroll
        for (int j = 0; j < 4; ++j)
            acc[i][j] = (f32x4_t){0.f, 0.f, 0.f, 0.f};
    gemm128_core(A, W, As, Ws, acc);

    const int tid = threadIdx.x, lane = tid & 63, quad = lane >> 4, l15 = lane & 15;
    const int wid = tid >> 6, wm = wid >> 1, wn = wid & 1;
    const int m0 = blockIdx.y * 128 + wm * 64;
    const int n0 = blockIdx.x * 128 + wn * 64;
    #pragma unroll
    for (int j = 0; j < 4; ++j) {
        const int n = n0 + j * 16 + l15;
        const float bn = bo[n];
        #pragma unroll
        for (int i = 0; i < 4; ++i)
            #pragma unroll
            for (int v = 0; v < 4; ++v) {
                const int m = m0 + i * 16 + quad * 4 + v;
                out[(size_t)m * 1024 + n] = acc[i][j][v] + bn;
            }
    }
}

// ---------------------------------------------------------------------------
// Kernel 3a: qrel GEMM. qrelG[bh][l][j] = Q[bh,l]·rel_k[j] (hi+lo), fp16 out.
// Barrier-free, no LDS: 4 waves/block, each wave does 16 rows x 272 cols.
__global__ __launch_bounds__(256) void qrel_kernel(
    const __bf16* __restrict__ Qh, const __bf16* __restrict__ relkp,
    _Float16* __restrict__ qrelG)
{
    const int tid = threadIdx.x, lane = tid & 63, wid = tid >> 6;
    const int quad = lane >> 4, l15 = lane & 15;
    const int bh = blockIdx.y;
    const int l0 = blockIdx.x * 64 + wid * 16;
    const __bf16* Qbase = Qh + (size_t)bh * 65536;
    const __bf16* relk_hi = relkp;
    const __bf16* relk_lo = relkp + 17408;
    const bf16x8_t aq0 = *(const bf16x8_t*)(Qbase + (l0 + l15) * 64 + quad * 8);
    const bf16x8_t aq1 = *(const bf16x8_t*)(Qbase + (l0 + l15) * 64 + 32 + quad * 8);
    _Float16* out = qrelG + ((size_t)bh * 1024 + l0) * 272;
    for (int nt = 0; nt < 17; ++nt) {
        const int j = nt * 16 + l15;
        const bf16x8_t h0  = *(const bf16x8_t*)(relk_hi + j * 64 + quad * 8);
        const bf16x8_t h1  = *(const bf16x8_t*)(relk_hi + j * 64 + 32 + quad * 8);
        const bf16x8_t lo0 = *(const bf16x8_t*)(relk_lo + j * 64 + quad * 8);
        const bf16x8_t lo1 = *(const bf16x8_t*)(relk_lo + j * 64 + 32 + quad * 8);
        f32x4_t c = (f32x4_t){0.f, 0.f, 0.f, 0.f};
        c = MFMA16(aq0, lo0, c);
        c = MFMA16(aq1, lo1, c);
        c = MFMA16(aq0, h0, c);
        c = MFMA16(aq1, h1, c);
        #pragma unroll
        for (int v = 0; v < 4; ++v)
            out[(quad * 4 + v) * 272 + j] = (_Float16)c[v];
    }
}

// ---------------------------------------------------------------------------
// Kernel 3b: fused attention. ONE wave per block (all LDS wave-private, ZERO
// barriers). 16 q-rows/wave. Diagonal-band split: far tiles (|r-l|>128 for the
// whole 16x16 subtile) use per-row register bias qrel[l][0]/qrel[l][256]; only
// ~9/32 k-tiles gather qrelG (fp16, L2/L3-hot). Single-pass softmax; rel_v via
// 257-bin histogram w then w @ rel_v^T MFMA into the same O accumulators.
__global__ __launch_bounds__(64, 4) void attn_kernel(
    const __bf16* __restrict__ Qh, const __bf16* __restrict__ Kh,
    const __bf16* __restrict__ VhT, const _Float16* __restrict__ qrelG,
    const __bf16* __restrict__ rvT, const int* __restrict__ mask,
    __bf16* __restrict__ ctx)
{
    __shared__ __align__(16) __bf16 w_s[16][288];
    __shared__ __align__(16) __bf16 p_s[16][40];   // pad 32->40: 8-way -> 4-way

    const int lane = threadIdx.x & 63;
    const int quad = lane >> 4, l15 = lane & 15;
    const int bh = blockIdx.y;
    const int b  = bh >> 4;
    const int l0 = blockIdx.x * 16;

    const __bf16* Qbase = Qh  + (size_t)bh * 65536;
    const __bf16* Kbase = Kh  + (size_t)bh * 65536;
    const __bf16* Vbase = VhT + (size_t)bh * 65536;
    const _Float16* qr  = qrelG + ((size_t)bh * 1024 + l0) * 272;

    // zero the w-bin array (16x288 bf16 = 576 dwords... 2304? 16*288*2B = 9216B = 2304 dwords)
    {
        uint4* wz = (uint4*)&w_s[0][0];
        for (int t = lane; t < 576; t += 64) wz[t] = (uint4){0u, 0u, 0u, 0u};
    }

    const bf16x8_t aq0 = *(const bf16x8_t*)(Qbase + (l0 + l15) * 64 + quad * 8);
    const bf16x8_t aq1 = *(const bf16x8_t*)(Qbase + (l0 + l15) * 64 + 32 + quad * 8);

    // per-row far-region bias constants (broadcast loads within quad)
    float c0[4], c1[4];
    #pragma unroll
    for (int v = 0; v < 4; ++v) {
        c0[v] = (float)qr[(quad * 4 + v) * 272 + 0];
        c1[v] = (float)qr[(quad * 4 + v) * 272 + 256];
    }

    f32x4_t o[4];
    #pragma unroll
    for (int dt = 0; dt < 4; ++dt) o[dt] = (f32x4_t){0.f, 0.f, 0.f, 0.f};
    float rowsum[4] = {0.f, 0.f, 0.f, 0.f};
    float e0[4] = {0.f, 0.f, 0.f, 0.f};
    float e1[4] = {0.f, 0.f, 0.f, 0.f};

    for (int rc = 0; rc < 32; ++rc) {
        const int r0 = rc * 32;
        #pragma unroll
        for (int nt = 0; nt < 2; ++nt) {
            const int rbase = r0 + nt * 16;
            const int r = rbase + l15;
            const bf16x8_t kb0 = *(const bf16x8_t*)(Kbase + r * 64 + quad * 8);
            const bf16x8_t kb1 = *(const bf16x8_t*)(Kbase + r * 64 + 32 + quad * 8);
            f32x4_t s = (f32x4_t){0.f, 0.f, 0.f, 0.f};
            s = MFMA16(aq0, kb0, s);
            s = MFMA16(aq1, kb1, s);
            const float madd = (mask[b * 1024 + r] == 0) ? -1.0e9f : 0.f;
            if (rbase + 15 - l0 <= -128) {            // far-lo: all j==0
                #pragma unroll
                for (int v = 0; v < 4; ++v) {
                    const float p = __expf(fmaf(s[v], SCALE, c0[v]) + madd);
                    const __bf16 pb = (__bf16)p; const float pf = (float)pb;
                    rowsum[v] += pf; e0[v] += pf;
                    p_s[quad * 4 + v][nt * 16 + l15] = pb;
                }
            } else if (rbase - (l0 + 15) >= 128) {    // far-hi: all j==256
                #pragma unroll
                for (int v = 0; v < 4; ++v) {
                    const float p = __expf(fmaf(s[v], SCALE, c1[v]) + madd);
                    const __bf16 pb = (__bf16)p; const float pf = (float)pb;
                    rowsum[v] += pf; e1[v] += pf;
                    p_s[quad * 4 + v][nt * 16 + l15] = pb;
                }
            } else {                                   // band: gather qrelG
                #pragma unroll
                for (int v = 0; v < 4; ++v) {
                    const int lrow = quad * 4 + v;
                    const int dd = r - (l0 + lrow);
                    int j = dd + 128; j = j < 0 ? 0 : (j > 256 ? 256 : j);
                    const float bias = (float)qr[lrow * 272 + j];
                    const float p = __expf(fmaf(s[v], SCALE, bias) + madd);
                    const __bf16 pb = (__bf16)p; const float pf = (float)pb;
                    rowsum[v] += pf;
                    p_s[lrow][nt * 16 + l15] = pb;
                    if (j == 0)        e0[v] += pf;
                    else if (j == 256) e1[v] += pf;
                    else               w_s[lrow][j] = pb;
                }
            }
        }
        // PV: wave-private LDS round-trip, no barrier (in-order DS + waitcnt)
        const bf16x8_t pa = *(const bf16x8_t*)(&p_s[l15][quad * 8]);
        #pragma unroll
        for (int dt = 0; dt < 4; ++dt) {
            const bf16x8_t vb =
                *(const bf16x8_t*)(Vbase + (dt * 16 + l15) * 1024 + r0 + quad * 8);
            o[dt] = MFMA16(pa, vb, o[dt]);
        }
    }

    // reduce row sums / edge bins across the 16 lanes of each quad
    #pragma unroll
    for (int v = 0; v < 4; ++v) {
        #pragma unroll
        for (int mm = 1; mm < 16; mm <<= 1) {
            rowsum[v] += __shfl_xor(rowsum[v], mm, 64);
            e0[v]     += __shfl_xor(e0[v], mm, 64);
            e1[v]     += __shfl_xor(e1[v], mm, 64);
        }
    }
    if (l15 == 0) {
        #pragma unroll
        for (int v = 0; v < 4; ++v) {
            w_s[quad * 4 + v][0]   = (__bf16)e0[v];
            w_s[quad * 4 + v][256] = (__bf16)e1[v];
        }
    }

    // O += w @ rel_v (K padded to 288 with zeros)
    for (int kc = 0; kc < 9; ++kc) {
        const bf16x8_t wa = *(const bf16x8_t*)(&w_s[l15][kc * 32 + quad * 8]);
        #pragma unroll
        for (int dt = 0; dt < 4; ++dt) {
            const bf16x8_t rb =
                *(const bf16x8_t*)(rvT + (dt * 16 + l15) * 288 + kc * 32 + quad * 8);
            o[dt] = MFMA16(wa, rb, o[dt]);
        }
    }

    // epilogue: fold in 1/rowsum, store ctx [b][s][h*64+d] bf16
    float rinv[4];
    #pragma unroll
    for (int v = 0; v < 4; ++v) rinv[v] = 1.f / rowsum[v];
    const int h = bh & 15;
    #pragma unroll
    for (int dt = 0; dt < 4; ++dt)
        #pragma unroll
        for (int v = 0; v < 4; ++v) {
            const int l = l0 + quad * 4 + v;
            ctx[((size_t)b * 1024 + l) * 1024 + h * 64 + dt * 16 + l15]
                = (__bf16)(o[dt][v] * rinv[v]);
        }
}

// ---------------------------------------------------------------------------
extern "C" void kernel_launch(void* const* d_in, const int* in_sizes, int n_in,
                              void* d_out, int out_size, void* d_ws, size_t ws_size,
                              hipStream_t stream)
{
    const float* q    = (const float*)d_in[0];
    const float* k    = (const float*)d_in[1];
    const float* v    = (const float*)d_in[2];
    const int*   mask = (const int*)  d_in[3];
    const float* wq   = (const float*)d_in[4];
    const float* bq   = (const float*)d_in[5];
    const float* wk   = (const float*)d_in[6];
    const float* bk   = (const float*)d_in[7];
    const float* wv   = (const float*)d_in[8];
    const float* bv   = (const float*)d_in[9];
    const float* wo   = (const float*)d_in[10];
    const float* bo   = (const float*)d_in[11];
    const float* relk = (const float*)d_in[12];
    const float* relv = (const float*)d_in[13];

    // workspace layout (bf16 elements); total 38,850,560 elems = 77.7 MB
    // NOTE: qrelG (fp16, 64*1024*272 = 17,825,792 elems) exactly overlays
    // [Xbf | Xqlo' ...] — no wait: it overlays the first 17,825,792 bf16 slots
    // = Xbf(12582912) + Xqlo(4194304) + Wqlo(1048576), all dead after gemm_qkv.
    __bf16* Xbf   = (__bf16*)d_ws;            // 12582912 (q,k,v inputs hi)
    __bf16* Xqlo  = Xbf   + 12582912;         // 4194304 (query input residual)
    __bf16* Wqlo  = Xqlo  + 4194304;          // 1048576 (wq residual)
    __bf16* Wall  = Wqlo  + 1048576;          // 4194304 (wq,wk,wv,wo hi)
    __bf16* QKVh  = Wall  + 4194304;          // 12582912 (Q,K row; V transposed)
    __bf16* ctx   = QKVh  + 12582912;         // 4194304
    __bf16* relkp = ctx   + 4194304;          // 34816 (hi | lo)
    __bf16* rvT   = relkp + 34816;            // 18432
    _Float16* qrelG = (_Float16*)d_ws;        // overlays Xbf|Xqlo|Wqlo after qkv

    cast_all_kernel<<<16419, 256, 0, stream>>>(q, k, v, wq, wk, wv, wo, relk, relv,
                                               Xbf, Wall, relkp, rvT, Xqlo, Wqlo);
    gemm_qkv_kernel<<<dim3(8, 32, 3), 256, 0, stream>>>(Xbf, Wall, Xqlo, Wqlo,
                                                        bq, bk, bv, QKVh);
    qrel_kernel<<<dim3(16, 64), 256, 0, stream>>>(QKVh, relkp, qrelG);
    attn_kernel<<<dim3(64, 64), 64, 0, stream>>>(QKVh, QKVh + 4194304,
                                                 QKVh + 2 * 4194304, qrelG, rvT,
                                                 mask, ctx);
    gemm_out_kernel<<<dim3(8, 32, 1), 256, 0, stream>>>(ctx, Wall + 3 * 1048576,
                                                        bo, (float*)d_out);
}